// Round 4
// baseline (732.873 us; speedup 1.0000x reference)
//
#include <hip/hip_runtime.h>
#include <hip/hip_bf16.h>

#define B_ 8
#define C_ 256
#define N_ 4096
#define D_ 16
#define TWO_C 512

#define BM2 256
#define BN2 256
#define BK2 32

typedef __bf16 bf16x8 __attribute__((ext_vector_type(8)));
typedef float f32x4 __attribute__((ext_vector_type(4)));
typedef unsigned short u16x4 __attribute__((ext_vector_type(4)));

static __device__ __forceinline__ unsigned short f2bf_rtn(float f) {
    unsigned int u = __builtin_bit_cast(unsigned int, f);
    u += 0x7fffu + ((u >> 16) & 1u);
    return (unsigned short)(u >> 16);
}

__device__ __forceinline__ void gld16(const void* g, void* l) {
    __builtin_amdgcn_global_load_lds(
        (const __attribute__((address_space(1))) unsigned int*)g,
        (__attribute__((address_space(3))) unsigned int*)l, 16, 0, 0);
}

// ---------------------------------------------------------------------------
// Kernel 1a: partial q/k over a 128-wide c-chunk. grid = B*16*4 = 512 blocks.
// ---------------------------------------------------------------------------
__global__ __launch_bounds__(256) void qk_part(
    const float* __restrict__ x1, const float* __restrict__ x2,
    const float* __restrict__ Wq, const float* __restrict__ Wk,
    float* __restrict__ pq, float* __restrict__ pk)
{
    const int tid = threadIdx.x;
    const int bid = blockIdx.x;
    const int ch = bid & 3;
    const int nt = (bid >> 2) & 15;
    const int b  = bid >> 6;
    const int n  = nt * 256 + tid;

    const float* xs  = (ch < 2) ? x1 : x2;
    const int xoff = (ch & 1) * 128;
    const int wcol = (ch >> 1) * 256 + xoff;

    const float* px = xs + ((size_t)b * C_ + xoff) * N_ + n;

    float aq[D_], ak[D_];
#pragma unroll
    for (int d = 0; d < D_; ++d) { aq[d] = 0.f; ak[d] = 0.f; }

    for (int c = 0; c < 128; ++c) {
        float xv = px[(size_t)c * N_];
#pragma unroll
        for (int d = 0; d < D_; ++d) {
            aq[d] += Wq[d * TWO_C + wcol + c] * xv;
            ak[d] += Wk[d * TWO_C + wcol + c] * xv;
        }
    }

    f32x4* q4 = (f32x4*)pq + (size_t)ch * B_ * N_ * 4 + ((size_t)b * N_ + n) * 4;
    f32x4* k4 = (f32x4*)pk + (size_t)ch * B_ * N_ * 4 + ((size_t)b * N_ + n) * 4;
#pragma unroll
    for (int j = 0; j < 4; ++j) {
        f32x4 tq = { aq[4*j], aq[4*j+1], aq[4*j+2], aq[4*j+3] };
        f32x4 tk = { ak[4*j], ak[4*j+1], ak[4*j+2], ak[4*j+3] };
        q4[j] = tq;
        k4[j] = tk;
    }
}

// ---------------------------------------------------------------------------
// Kernel 1b: reduce 4 partials + bias, emit bf16 q/k in [B][N][32] layout
// (d = 16..31 zero-padded for the K=32 MFMA). grid = 512 blocks of 256.
// ---------------------------------------------------------------------------
__global__ __launch_bounds__(256) void qk_reduce(
    const float* __restrict__ pq, const float* __restrict__ pk,
    const float* __restrict__ bq, const float* __restrict__ bk,
    unsigned short* __restrict__ qbf, unsigned short* __restrict__ kbf)
{
    const int tg = blockIdx.x * 256 + threadIdx.x;  // f32x4 group index
    const int row = tg >> 2;                        // b*N + n
    const int d4  = tg & 3;
    const f32x4* pq4 = (const f32x4*)pq;
    const f32x4* pk4 = (const f32x4*)pk;
    f32x4 q = ((const f32x4*)bq)[d4];
    f32x4 k = ((const f32x4*)bk)[d4];
    const size_t stride = (size_t)B_ * N_ * 4;
#pragma unroll
    for (int ch = 0; ch < 4; ++ch) {
        q += pq4[ch * stride + tg];
        k += pk4[ch * stride + tg];
    }
    u16x4 qo = { f2bf_rtn(q[0]), f2bf_rtn(q[1]), f2bf_rtn(q[2]), f2bf_rtn(q[3]) };
    u16x4 ko = { f2bf_rtn(k[0]), f2bf_rtn(k[1]), f2bf_rtn(k[2]), f2bf_rtn(k[3]) };
    u16x4 z  = { 0, 0, 0, 0 };
    *(u16x4*)(qbf + (size_t)row * 32 + d4 * 4)      = qo;
    *(u16x4*)(qbf + (size_t)row * 32 + 16 + d4 * 4) = z;
    *(u16x4*)(kbf + (size_t)row * 32 + d4 * 4)      = ko;
    *(u16x4*)(kbf + (size_t)row * 32 + 16 + d4 * 4) = z;
}

// ---------------------------------------------------------------------------
// Kernel 2: v = Wv @ x + bv, bf16 into stacked layout [B][512][N].
// ---------------------------------------------------------------------------
#define VO 16
__global__ __launch_bounds__(256) void v_kernel(
    const float* __restrict__ x1, const float* __restrict__ x2,
    const float* __restrict__ Wv1, const float* __restrict__ bv1,
    const float* __restrict__ Wv2, const float* __restrict__ bv2,
    unsigned short* __restrict__ vstack)
{
    const int tid = threadIdx.x;
    const unsigned bi = blockIdx.x;
    const int wv = bi & 1;
    const int mt = (bi >> 1) & 15;
    const int og = (bi >> 5) & 15;
    const int b  = bi >> 9;
    const int m  = (mt << 8) + tid;
    const int o0 = og * VO;

    const float* x    = wv ? x2 : x1;
    const float* W    = wv ? Wv2 : Wv1;
    const float* bias = wv ? bv2 : bv1;

    float acc[VO];
#pragma unroll
    for (int i = 0; i < VO; ++i) acc[i] = bias[o0 + i];

    const float* px = x + (size_t)b * C_ * N_ + m;
    for (int c = 0; c < C_; ++c) {
        float xv = px[(size_t)c * N_];
#pragma unroll
        for (int i = 0; i < VO; ++i)
            acc[i] += W[(o0 + i) * C_ + c] * xv;
    }

#pragma unroll
    for (int i = 0; i < VO; ++i)
        vstack[((size_t)b * 512 + wv * 256 + o0 + i) * N_ + m] = f2bf_rtn(acc[i]);
}

// ---------------------------------------------------------------------------
// Kernel 3: attention via MFMA energies, two-pass (sum, then write), no LDS.
// grid = B * (N/64) = 512 blocks of 256 (4 waves = 64 rows).
// ---------------------------------------------------------------------------
__global__ __launch_bounds__(256) void att_mfma(
    const unsigned short* __restrict__ qbf,
    const unsigned short* __restrict__ kbf,
    float* __restrict__ att)
{
    const int tid  = threadIdx.x;
    const int lane = tid & 63;
    const int wid  = tid >> 6;
    const int b  = blockIdx.x >> 6;
    const int n0 = (blockIdx.x & 63) * 64 + wid * 16;
    const int col = lane & 15;       // n within tile
    const int grp = lane >> 4;       // k-group / m-subgroup

    const bf16x8 qfrag = *reinterpret_cast<const bf16x8*>(
        qbf + ((size_t)b * N_ + n0 + col) * 32 + grp * 8);
    const unsigned short* kp = kbf + ((size_t)b * N_ + col) * 32 + grp * 8;
    float* ap = att + (size_t)b * N_ * N_ + (size_t)(n0 + col) * N_ + grp * 4;

    const f32x4 zero = {0.f, 0.f, 0.f, 0.f};

    float sum = 0.f;
#pragma unroll 4
    for (int t = 0; t < 256; ++t) {
        bf16x8 kf = *reinterpret_cast<const bf16x8*>(kp + (size_t)t * 512);
        f32x4 e = __builtin_amdgcn_mfma_f32_16x16x32_bf16(kf, qfrag, zero, 0, 0, 0);
        sum += __expf(e[0]) + __expf(e[1]) + __expf(e[2]) + __expf(e[3]);
    }
    sum += __shfl_xor(sum, 16);
    sum += __shfl_xor(sum, 32);
    const float inv = 1.f / sum;

#pragma unroll 4
    for (int t = 0; t < 256; ++t) {
        bf16x8 kf = *reinterpret_cast<const bf16x8*>(kp + (size_t)t * 512);
        f32x4 e = __builtin_amdgcn_mfma_f32_16x16x32_bf16(kf, qfrag, zero, 0, 0, 0);
        f32x4 p = { __expf(e[0]) * inv, __expf(e[1]) * inv,
                    __expf(e[2]) * inv, __expf(e[3]) * inv };
        *reinterpret_cast<f32x4*>(ap + (size_t)t * 16) = p;
    }
}

// ---------------------------------------------------------------------------
// Kernel 4: PV GEMM, 2-phase double-buffered (catalog minimum recipe).
// Per batch: D[c,n] = sum_m V[c,m]*att[n,m], c in [0,512) stacked V1/V2.
// BM=256 x BN=256, BK=32, 512 threads = 8 waves (2M x 4N), 128x64 per wave,
// acc[8][4]. A via global_load_lds (linear LDS dest, per-lane global src);
// B loads issued early (f32), cvt+ds_write after compute (T14 overlap).
// One barrier per K-tile; buffers alternate. LDS = 64 KB static.
// grid = 8(b) x 16(nt) x 2(ct) = 256 blocks; XCD swizzle: one batch per XCD,
// ct-pairs adjacent so att K-panels are L2-shared.
// ---------------------------------------------------------------------------
__global__ __launch_bounds__(512, 2) void pv_gemm2(
    const unsigned short* __restrict__ vstack,
    const float* __restrict__ att,
    const float* __restrict__ x1, const float* __restrict__ x2,
    float* __restrict__ out1, float* __restrict__ out2)
{
    __shared__ unsigned short Asm[2][BM2 * BK2];   // 2 x 16 KB
    __shared__ unsigned short Bsm[2][BN2 * BK2];   // 2 x 16 KB

    const int tid  = threadIdx.x;
    const int lane = tid & 63;
    const int wid  = tid >> 6;
    const int wr   = wid >> 2;     // 0..1 : M offset *128
    const int wc   = wid & 3;      // 0..3 : N offset *64

    // bijective XCD swizzle: nwg=256, 32 per XCD
    const int bid  = blockIdx.x;
    const int orig = (bid & 7) * 32 + (bid >> 3);
    const int ct = orig & 1;
    const int nt = (orig >> 1) & 15;
    const int b  = orig >> 5;
    const int n0 = nt * BN2;

    const unsigned short* Vb = vstack + ((size_t)b * 512 + ct * 256) * N_;
    const float* Ab = att + (size_t)b * N_ * N_;

    // staging chunk ids: qa0 = tid, qa1 = tid+512; row = q>>2, col8 = (q&3)*8
    const int qa0 = tid, qa1 = tid + 512;
    const unsigned short* pa0 = Vb + (size_t)(qa0 >> 2) * N_ + (qa0 & 3) * 8;
    const unsigned short* pa1 = Vb + (size_t)(qa1 >> 2) * N_ + (qa1 & 3) * 8;
    const float* pb0 = Ab + (size_t)(n0 + (qa0 >> 2)) * N_ + (qa0 & 3) * 8;
    const float* pb1 = Ab + (size_t)(n0 + (qa1 >> 2)) * N_ + (qa1 & 3) * 8;

    const int row16 = lane & 15;
    const int koff  = (lane >> 4) * 8;

    f32x4 acc[8][4];
#pragma unroll
    for (int ai = 0; ai < 8; ++ai)
#pragma unroll
        for (int bj = 0; bj < 4; ++bj)
            acc[ai][bj] = (f32x4){0.f, 0.f, 0.f, 0.f};

    // ---- prologue: tile 0 into buf 0 ----
    {
        gld16(pa0, &Asm[0][qa0 * 8]);
        gld16(pa1, &Asm[0][qa1 * 8]);
        f32x4 b00 = *reinterpret_cast<const f32x4*>(pb0);
        f32x4 b01 = *reinterpret_cast<const f32x4*>(pb0 + 4);
        f32x4 b10 = *reinterpret_cast<const f32x4*>(pb1);
        f32x4 b11 = *reinterpret_cast<const f32x4*>(pb1 + 4);
        bf16x8 t0, t1;
#pragma unroll
        for (int j = 0; j < 4; ++j) {
            t0[j] = (__bf16)b00[j]; t0[4 + j] = (__bf16)b01[j];
            t1[j] = (__bf16)b10[j]; t1[4 + j] = (__bf16)b11[j];
        }
        *reinterpret_cast<bf16x8*>(&Bsm[0][qa0 * 8]) = t0;
        *reinterpret_cast<bf16x8*>(&Bsm[0][qa1 * 8]) = t1;
        __syncthreads();
    }

    int cur = 0;
    for (int kt = 0; kt < 127; ++kt) {
        const int nxt = cur ^ 1;
        const int ko = (kt + 1) * BK2;
        // issue next-tile A staging + B loads BEFORE compute
        gld16(pa0 + ko, &Asm[nxt][qa0 * 8]);
        gld16(pa1 + ko, &Asm[nxt][qa1 * 8]);
        f32x4 b00 = *reinterpret_cast<const f32x4*>(pb0 + ko);
        f32x4 b01 = *reinterpret_cast<const f32x4*>(pb0 + ko + 4);
        f32x4 b10 = *reinterpret_cast<const f32x4*>(pb1 + ko);
        f32x4 b11 = *reinterpret_cast<const f32x4*>(pb1 + ko + 4);

        // compute current tile
        {
            const unsigned short* As = &Asm[cur][0];
            const unsigned short* Bs = &Bsm[cur][0];
            bf16x8 af[8], bf[4];
#pragma unroll
            for (int ai = 0; ai < 8; ++ai)
                af[ai] = *reinterpret_cast<const bf16x8*>(
                    As + (wr * 128 + ai * 16 + row16) * BK2 + koff);
#pragma unroll
            for (int bj = 0; bj < 4; ++bj)
                bf[bj] = *reinterpret_cast<const bf16x8*>(
                    Bs + (wc * 64 + bj * 16 + row16) * BK2 + koff);
#pragma unroll
            for (int ai = 0; ai < 8; ++ai)
#pragma unroll
                for (int bj = 0; bj < 4; ++bj)
                    acc[ai][bj] = __builtin_amdgcn_mfma_f32_16x16x32_bf16(
                        af[ai], bf[bj], acc[ai][bj], 0, 0, 0);
        }

        // write next B tile (loads have had the compute phase to land)
        {
            bf16x8 t0, t1;
#pragma unroll
            for (int j = 0; j < 4; ++j) {
                t0[j] = (__bf16)b00[j]; t0[4 + j] = (__bf16)b01[j];
                t1[j] = (__bf16)b10[j]; t1[4 + j] = (__bf16)b11[j];
            }
            *reinterpret_cast<bf16x8*>(&Bsm[nxt][qa0 * 8]) = t0;
            *reinterpret_cast<bf16x8*>(&Bsm[nxt][qa1 * 8]) = t1;
        }
        __syncthreads();   // drains vmcnt (gld16) + lgkm (ds_write)
        cur = nxt;
    }

    // ---- final tile ----
    {
        const unsigned short* As = &Asm[cur][0];
        const unsigned short* Bs = &Bsm[cur][0];
        bf16x8 af[8], bf[4];
#pragma unroll
        for (int ai = 0; ai < 8; ++ai)
            af[ai] = *reinterpret_cast<const bf16x8*>(
                As + (wr * 128 + ai * 16 + row16) * BK2 + koff);
#pragma unroll
        for (int bj = 0; bj < 4; ++bj)
            bf[bj] = *reinterpret_cast<const bf16x8*>(
                Bs + (wc * 64 + bj * 16 + row16) * BK2 + koff);
#pragma unroll
        for (int ai = 0; ai < 8; ++ai)
#pragma unroll
            for (int bj = 0; bj < 4; ++bj)
                acc[ai][bj] = __builtin_amdgcn_mfma_f32_16x16x32_bf16(
                    af[ai], bf[bj], acc[ai][bj], 0, 0, 0);
    }

    float* outp      = ct ? out2 : out1;
    const float* xp  = ct ? x2 : x1;
#pragma unroll
    for (int ai = 0; ai < 8; ++ai) {
        const int c_l = wr * 128 + ai * 16 + (lane >> 4) * 4;
#pragma unroll
        for (int bj = 0; bj < 4; ++bj) {
            const int n = n0 + wc * 64 + bj * 16 + row16;
#pragma unroll
            for (int r = 0; r < 4; ++r) {
                const size_t idx = ((size_t)b * C_ + c_l + r) * N_ + n;
                outp[idx] = acc[ai][bj][r] + xp[idx];
            }
        }
    }
}

// ---------------------------------------------------------------------------
extern "C" void kernel_launch(void* const* d_in, const int* in_sizes, int n_in,
                              void* d_out, int out_size, void* d_ws, size_t ws_size,
                              hipStream_t stream)
{
    const float* x1  = (const float*)d_in[0];
    const float* x2  = (const float*)d_in[1];
    const float* Wq  = (const float*)d_in[2];
    const float* bq  = (const float*)d_in[3];
    const float* Wk  = (const float*)d_in[4];
    const float* bk  = (const float*)d_in[5];
    const float* Wv1 = (const float*)d_in[6];
    const float* bv1 = (const float*)d_in[7];
    const float* Wv2 = (const float*)d_in[8];
    const float* bv2 = (const float*)d_in[9];

    float* out  = (float*)d_out;
    float* out1 = out;
    float* out2 = out + (size_t)B_ * C_ * N_;
    float* att  = out + 2 * (size_t)B_ * C_ * N_;

    char* ws = (char*)d_ws;
    unsigned short* qbf = (unsigned short*)ws;                                  // 2 MB
    unsigned short* kbf = (unsigned short*)(ws + (size_t)2 * 1024 * 1024);      // 2 MB
    unsigned short* vstack = (unsigned short*)(ws + (size_t)4 * 1024 * 1024);   // 32 MB
    float* pq = (float*)(ws + (size_t)36 * 1024 * 1024);                        // 8 MB
    float* pk = (float*)(ws + (size_t)44 * 1024 * 1024);                        // 8 MB

    qk_part<<<B_ * 16 * 4, 256, 0, stream>>>(x1, x2, Wq, Wk, pq, pk);
    qk_reduce<<<(B_ * N_ * 4) / 256, 256, 0, stream>>>(pq, pk, bq, bk, qbf, kbf);
    v_kernel<<<B_ * 16 * 16 * 2, 256, 0, stream>>>(x1, x2, Wv1, bv1, Wv2, bv2, vstack);
    att_mfma<<<B_ * (N_ / 64), 256, 0, stream>>>(qbf, kbf, att);
    pv_gemm2<<<256, 512, 0, stream>>>(vstack, att, x1, x2, out1, out2);
}

// Round 5
// 569.274 us; speedup vs baseline: 1.2874x; 1.2874x over previous
//
#include <hip/hip_runtime.h>
#include <hip/hip_bf16.h>

#define B_ 8
#define C_ 256
#define N_ 4096
#define D_ 16
#define TWO_C 512

typedef __bf16 bf16x8 __attribute__((ext_vector_type(8)));
typedef float f32x4 __attribute__((ext_vector_type(4)));
typedef unsigned short u16x4 __attribute__((ext_vector_type(4)));

static __device__ __forceinline__ unsigned short f2bf_rtn(float f) {
    unsigned int u = __builtin_bit_cast(unsigned int, f);
    u += 0x7fffu + ((u >> 16) & 1u);
    return (unsigned short)(u >> 16);
}

__device__ __forceinline__ void gld16(const void* g, void* l) {
    __builtin_amdgcn_global_load_lds(
        (const __attribute__((address_space(1))) unsigned int*)g,
        (__attribute__((address_space(3))) unsigned int*)l, 16, 0, 0);
}

#define MF(K, Q) __builtin_amdgcn_mfma_f32_16x16x32_bf16((K), (Q), zerov, 0, 0, 0)

// ---------------------------------------------------------------------------
// Kernel 1a: partial q/k over a 128-wide c-chunk. grid = B*16*4 = 512 blocks.
// ---------------------------------------------------------------------------
__global__ __launch_bounds__(256) void qk_part(
    const float* __restrict__ x1, const float* __restrict__ x2,
    const float* __restrict__ Wq, const float* __restrict__ Wk,
    float* __restrict__ pq, float* __restrict__ pk)
{
    const int tid = threadIdx.x;
    const int bid = blockIdx.x;
    const int ch = bid & 3;
    const int nt = (bid >> 2) & 15;
    const int b  = bid >> 6;
    const int n  = nt * 256 + tid;

    const float* xs  = (ch < 2) ? x1 : x2;
    const int xoff = (ch & 1) * 128;
    const int wcol = (ch >> 1) * 256 + xoff;

    const float* px = xs + ((size_t)b * C_ + xoff) * N_ + n;

    float aq[D_], ak[D_];
#pragma unroll
    for (int d = 0; d < D_; ++d) { aq[d] = 0.f; ak[d] = 0.f; }

    for (int c = 0; c < 128; ++c) {
        float xv = px[(size_t)c * N_];
#pragma unroll
        for (int d = 0; d < D_; ++d) {
            aq[d] += Wq[d * TWO_C + wcol + c] * xv;
            ak[d] += Wk[d * TWO_C + wcol + c] * xv;
        }
    }

    f32x4* q4 = (f32x4*)pq + (size_t)ch * B_ * N_ * 4 + ((size_t)b * N_ + n) * 4;
    f32x4* k4 = (f32x4*)pk + (size_t)ch * B_ * N_ * 4 + ((size_t)b * N_ + n) * 4;
#pragma unroll
    for (int j = 0; j < 4; ++j) {
        f32x4 tq = { aq[4*j], aq[4*j+1], aq[4*j+2], aq[4*j+3] };
        f32x4 tk = { ak[4*j], ak[4*j+1], ak[4*j+2], ak[4*j+3] };
        q4[j] = tq;
        k4[j] = tk;
    }
}

// ---------------------------------------------------------------------------
// Kernel 1b: reduce 4 partials + bias, emit bf16 q/k in [B][N][32] layout
// (d = 16..31 zero-padded for the K=32 MFMA). grid = 512 blocks of 256.
// ---------------------------------------------------------------------------
__global__ __launch_bounds__(256) void qk_reduce(
    const float* __restrict__ pq, const float* __restrict__ pk,
    const float* __restrict__ bq, const float* __restrict__ bk,
    unsigned short* __restrict__ qbf, unsigned short* __restrict__ kbf)
{
    const int tg = blockIdx.x * 256 + threadIdx.x;  // f32x4 group index
    const int row = tg >> 2;                        // b*N + n
    const int d4  = tg & 3;
    const f32x4* pq4 = (const f32x4*)pq;
    const f32x4* pk4 = (const f32x4*)pk;
    f32x4 q = ((const f32x4*)bq)[d4];
    f32x4 k = ((const f32x4*)bk)[d4];
    const size_t stride = (size_t)B_ * N_ * 4;
#pragma unroll
    for (int ch = 0; ch < 4; ++ch) {
        q += pq4[ch * stride + tg];
        k += pk4[ch * stride + tg];
    }
    u16x4 qo = { f2bf_rtn(q[0]), f2bf_rtn(q[1]), f2bf_rtn(q[2]), f2bf_rtn(q[3]) };
    u16x4 ko = { f2bf_rtn(k[0]), f2bf_rtn(k[1]), f2bf_rtn(k[2]), f2bf_rtn(k[3]) };
    u16x4 z  = { 0, 0, 0, 0 };
    *(u16x4*)(qbf + (size_t)row * 32 + d4 * 4)      = qo;
    *(u16x4*)(qbf + (size_t)row * 32 + 16 + d4 * 4) = z;
    *(u16x4*)(kbf + (size_t)row * 32 + d4 * 4)      = ko;
    *(u16x4*)(kbf + (size_t)row * 32 + 16 + d4 * 4) = z;
}

// ---------------------------------------------------------------------------
// Kernel 2: v = Wv @ x + bv, bf16 into stacked layout [B][512][N].
// ---------------------------------------------------------------------------
#define VO 16
__global__ __launch_bounds__(256) void v_kernel(
    const float* __restrict__ x1, const float* __restrict__ x2,
    const float* __restrict__ Wv1, const float* __restrict__ bv1,
    const float* __restrict__ Wv2, const float* __restrict__ bv2,
    unsigned short* __restrict__ vstack)
{
    const int tid = threadIdx.x;
    const unsigned bi = blockIdx.x;
    const int wv = bi & 1;
    const int mt = (bi >> 1) & 15;
    const int og = (bi >> 5) & 15;
    const int b  = bi >> 9;
    const int m  = (mt << 8) + tid;
    const int o0 = og * VO;

    const float* x    = wv ? x2 : x1;
    const float* W    = wv ? Wv2 : Wv1;
    const float* bias = wv ? bv2 : bv1;

    float acc[VO];
#pragma unroll
    for (int i = 0; i < VO; ++i) acc[i] = bias[o0 + i];

    const float* px = x + (size_t)b * C_ * N_ + m;
    for (int c = 0; c < C_; ++c) {
        float xv = px[(size_t)c * N_];
#pragma unroll
        for (int i = 0; i < VO; ++i)
            acc[i] += W[(o0 + i) * C_ + c] * xv;
    }

#pragma unroll
    for (int i = 0; i < VO; ++i)
        vstack[((size_t)b * 512 + wv * 256 + o0 + i) * N_ + m] = f2bf_rtn(acc[i]);
}

// ---------------------------------------------------------------------------
// Kernel 3: FUSED attention + PV.
// Per block (b, ct, nt): out_ct[c=0..255, n=nt*256..+256] and (split by ct)
// the f32 attention rows for those n.
// Phase 1 (K-loop over m, BK=32):
//   - E-tile: e = mfma(k_rows, q_cols) -> lane holds e[m0+grp*4+r][n] (validated
//     layout). exp -> rowsum accumulate + bf16 pack -> Bsm (XOR-swizzled).
//   - A (V-panel rows, stacked v1/v2 ct half) via global_load_lds, source
//     pre-swizzled so LDS stays linear (rule #21), double-buffered; k-frags
//     prefetched one step ahead. __syncthreads at step top drains prefetch;
//     raw lgkmcnt(0)+s_barrier after staging keeps next A-prefetch in flight.
//   - PV: 12 swizzled ds_read_b128 + 32 MFMA per wave per step.
// Epilogue: out = acc * inv[n] + x (inv via shfl-reduced rowsums -> LDS).
// Phase 2: recompute bit-identical e-tiles for this ct's m-half, write
//   att[n][m] = exp(e)*inv[n] as full-line f32x4 stores.
// grid = 256 blocks (8b x 2ct x 16nt), 512 threads (8 waves, 2M x 4N).
// ---------------------------------------------------------------------------
__global__ __launch_bounds__(512) void fused_pv(
    const unsigned short* __restrict__ qbf,
    const unsigned short* __restrict__ kbf,
    const unsigned short* __restrict__ vstack,
    const float* __restrict__ x1, const float* __restrict__ x2,
    float* __restrict__ out1, float* __restrict__ out2,
    float* __restrict__ att)
{
    __shared__ unsigned short Asm[2][256 * 32];  // 2 x 16 KB, V tile
    __shared__ unsigned short Bsm[256 * 32];     // 16 KB, P tile (bf16)
    __shared__ float sinv[256];

    const int tid  = threadIdx.x;
    const int lane = tid & 63;
    const int wid  = tid >> 6;
    const int wr   = wid >> 2;      // 0..1 : c-offset *128
    const int wc   = wid & 3;       // 0..3 : n-offset *64
    const int col  = lane & 15;
    const int grp  = lane >> 4;

    // bijective XCD swizzle: nwg=256, 32/XCD -> one batch per XCD
    const int bid  = blockIdx.x;
    const int orig = (bid & 7) * 32 + (bid >> 3);
    const int nt = orig & 15;
    const int ct = (orig >> 4) & 1;
    const int b  = orig >> 5;
    const int n0 = nt * 256;

    const f32x4 zerov = {0.f, 0.f, 0.f, 0.f};

    // ---- q fragments (B-operand of energy MFMA), one per 16-n subtile ----
    const bf16x8 qf0 = *(const bf16x8*)(qbf + ((size_t)b * N_ + n0 + wid * 32 + col) * 32 + grp * 8);
    const bf16x8 qf1 = *(const bf16x8*)(qbf + ((size_t)b * N_ + n0 + wid * 32 + 16 + col) * 32 + grp * 8);

    // ---- k fragment source (A-operand of energy MFMA) ----
    const unsigned short* kbase = kbf + ((size_t)b * N_ + col) * 32 + grp * 8;

    // ---- A (V) staging: pre-swizzled global source, linear LDS dest ----
    const unsigned short* Vb = vstack + ((size_t)b * 512 + ct * 256) * N_;
    const int q0 = tid, q1 = tid + 512;
    const unsigned short* pa0 = Vb + (size_t)(q0 >> 2) * N_ + (((q0 & 3) ^ ((q0 >> 2) & 3)) * 8);
    const unsigned short* pa1 = Vb + (size_t)(q1 >> 2) * N_ + (((q1 & 3) ^ ((q1 >> 2) & 3)) * 8);

    // ---- Bsm write pointers (XOR-swizzled on 16B units), thread-const ----
    const int nl0 = wid * 32 + col, nl1 = nl0 + 16;
    u16x4* bw00 = (u16x4*)((char*)Bsm + nl0 * 64 + ((((grp >> 1))     ^ (nl0 & 3)) << 4) + (grp & 1) * 8);
    u16x4* bw01 = (u16x4*)((char*)Bsm + nl0 * 64 + (((2 + (grp >> 1)) ^ (nl0 & 3)) << 4) + (grp & 1) * 8);
    u16x4* bw10 = (u16x4*)((char*)Bsm + nl1 * 64 + ((((grp >> 1))     ^ (nl1 & 3)) << 4) + (grp & 1) * 8);
    u16x4* bw11 = (u16x4*)((char*)Bsm + nl1 * 64 + (((2 + (grp >> 1)) ^ (nl1 & 3)) << 4) + (grp & 1) * 8);

    // ---- fragment read offsets (XOR-swizzled), thread-const ----
    int raOff[8], rbOff[4];
#pragma unroll
    for (int ai = 0; ai < 8; ++ai) {
        const int rowA = wr * 128 + ai * 16 + col;
        raOff[ai] = rowA * 64 + ((grp ^ (rowA & 3)) << 4);
    }
#pragma unroll
    for (int bj = 0; bj < 4; ++bj) {
        const int nlb = wc * 64 + bj * 16 + col;
        rbOff[bj] = nlb * 64 + ((grp ^ (nlb & 3)) << 4);
    }

    f32x4 acc[8][4];
#pragma unroll
    for (int ai = 0; ai < 8; ++ai)
#pragma unroll
        for (int bj = 0; bj < 4; ++bj)
            acc[ai][bj] = zerov;

    float rsum0 = 0.f, rsum1 = 0.f;

    // ---- prologue: stage tile 0, load k-frags for tile 0 ----
    gld16(pa0, &Asm[0][tid * 8]);
    gld16(pa1, &Asm[0][tid * 8 + 4096]);
    pa0 += 32; pa1 += 32;
    bf16x8 kA0 = *(const bf16x8*)kbase;
    bf16x8 kA1 = *(const bf16x8*)(kbase + 512);
    const unsigned short* kp = kbase + 1024;

#define EMIT(E, RS, BW) do {                                                  \
    float p0 = __expf((E)[0]), p1 = __expf((E)[1]);                           \
    float p2 = __expf((E)[2]), p3 = __expf((E)[3]);                           \
    RS += (p0 + p1) + (p2 + p3);                                              \
    u16x4 pkv = { f2bf_rtn(p0), f2bf_rtn(p1), f2bf_rtn(p2), f2bf_rtn(p3) };   \
    *(BW) = pkv;                                                              \
} while (0)

    auto step = [&](int T, const unsigned short* AsCur, unsigned short* AsNxt,
                    const bf16x8& kc0, const bf16x8& kc1,
                    bf16x8& kn0, bf16x8& kn1) {
        __syncthreads();                       // drains prev prefetch (vmcnt 0)
        if (T < 127) {
            gld16(pa0, AsNxt + tid * 8);
            gld16(pa1, AsNxt + tid * 8 + 4096);
            pa0 += 32; pa1 += 32;
        }
        // energy tiles for this K-step
        f32x4 e00 = MF(kc0, qf0);
        f32x4 e01 = MF(kc1, qf0);
        f32x4 e10 = MF(kc0, qf1);
        f32x4 e11 = MF(kc1, qf1);
        if (T < 127) {                          // prefetch k for next step
            kn0 = *(const bf16x8*)kp;
            kn1 = *(const bf16x8*)(kp + 512);
            kp += 1024;
        }
        EMIT(e00, rsum0, bw00);
        EMIT(e01, rsum0, bw01);
        EMIT(e10, rsum1, bw10);
        EMIT(e11, rsum1, bw11);
        asm volatile("s_waitcnt lgkmcnt(0)" ::: "memory");  // Bsm writes visible
        __builtin_amdgcn_s_barrier();                        // A-prefetch stays in flight
        __builtin_amdgcn_sched_barrier(0);
        // PV MFMAs
        bf16x8 af[8], bfr[4];
#pragma unroll
        for (int ai = 0; ai < 8; ++ai)
            af[ai] = *(const bf16x8*)((const char*)AsCur + raOff[ai]);
#pragma unroll
        for (int bj = 0; bj < 4; ++bj)
            bfr[bj] = *(const bf16x8*)((const char*)Bsm + rbOff[bj]);
#pragma unroll
        for (int ai = 0; ai < 8; ++ai)
#pragma unroll
            for (int bj = 0; bj < 4; ++bj)
                acc[ai][bj] = __builtin_amdgcn_mfma_f32_16x16x32_bf16(
                    af[ai], bfr[bj], acc[ai][bj], 0, 0, 0);
    };

    bf16x8 kB0, kB1;
    for (int tt = 0; tt < 64; ++tt) {
        step(2 * tt,     &Asm[0][0], &Asm[1][0], kA0, kA1, kB0, kB1);
        step(2 * tt + 1, &Asm[1][0], &Asm[0][0], kB0, kB1, kA0, kA1);
    }

    // ---- rowsums -> inv ----
    rsum0 += __shfl_xor(rsum0, 16); rsum0 += __shfl_xor(rsum0, 32);
    rsum1 += __shfl_xor(rsum1, 16); rsum1 += __shfl_xor(rsum1, 32);
    const float inv0 = 1.f / rsum0;
    const float inv1 = 1.f / rsum1;
    if (lane < 16) {
        sinv[wid * 32 + lane]      = inv0;
        sinv[wid * 32 + 16 + lane] = inv1;
    }
    __syncthreads();

    // ---- epilogue: out = acc * inv + x ----
    float* outp     = ct ? out2 : out1;
    const float* xp = ct ? x2 : x1;
    float sc[4];
#pragma unroll
    for (int bj = 0; bj < 4; ++bj) sc[bj] = sinv[wc * 64 + bj * 16 + col];
#pragma unroll
    for (int ai = 0; ai < 8; ++ai) {
        const int c_l = wr * 128 + ai * 16 + grp * 4;
#pragma unroll
        for (int bj = 0; bj < 4; ++bj) {
            const int n = n0 + wc * 64 + bj * 16 + col;
#pragma unroll
            for (int r = 0; r < 4; ++r) {
                const size_t idx = ((size_t)b * C_ + c_l + r) * N_ + n;
                outp[idx] = acc[ai][bj][r] * sc[bj] + xp[idx];
            }
        }
    }

    // ---- phase 2: recompute e, write normalized att for this ct's m-half ----
    const unsigned short* kp2 = kbase + (size_t)(ct * 2048) * 32;
    float* ar0 = att + (size_t)b * N_ * N_ + (size_t)(n0 + wid * 32 + col) * N_;
    float* ar1 = ar0 + (size_t)16 * N_;

#define WRA(E, ROW, MOFF, INV) do {                                           \
    f32x4 pv = { __expf((E)[0]) * (INV), __expf((E)[1]) * (INV),              \
                 __expf((E)[2]) * (INV), __expf((E)[3]) * (INV) };            \
    *(f32x4*)((ROW) + (MOFF)) = pv;                                           \
} while (0)

    for (int s = 0; s < 64; ++s) {
        const int m0 = ct * 2048 + s * 32;
        bf16x8 k0 = *(const bf16x8*)kp2;
        bf16x8 k1 = *(const bf16x8*)(kp2 + 512);
        kp2 += 1024;
        f32x4 e00 = MF(k0, qf0);
        f32x4 e01 = MF(k1, qf0);
        f32x4 e10 = MF(k0, qf1);
        f32x4 e11 = MF(k1, qf1);
        WRA(e00, ar0, m0 + grp * 4,      inv0);
        WRA(e01, ar0, m0 + 16 + grp * 4, inv0);
        WRA(e10, ar1, m0 + grp * 4,      inv1);
        WRA(e11, ar1, m0 + 16 + grp * 4, inv1);
    }
#undef EMIT
#undef WRA
}

// ---------------------------------------------------------------------------
extern "C" void kernel_launch(void* const* d_in, const int* in_sizes, int n_in,
                              void* d_out, int out_size, void* d_ws, size_t ws_size,
                              hipStream_t stream)
{
    const float* x1  = (const float*)d_in[0];
    const float* x2  = (const float*)d_in[1];
    const float* Wq  = (const float*)d_in[2];
    const float* bq  = (const float*)d_in[3];
    const float* Wk  = (const float*)d_in[4];
    const float* bk  = (const float*)d_in[5];
    const float* Wv1 = (const float*)d_in[6];
    const float* bv1 = (const float*)d_in[7];
    const float* Wv2 = (const float*)d_in[8];
    const float* bv2 = (const float*)d_in[9];

    float* out  = (float*)d_out;
    float* out1 = out;
    float* out2 = out + (size_t)B_ * C_ * N_;
    float* att  = out + 2 * (size_t)B_ * C_ * N_;

    char* ws = (char*)d_ws;
    unsigned short* qbf = (unsigned short*)ws;                                  // 2 MB [B][N][32]
    unsigned short* kbf = (unsigned short*)(ws + (size_t)2 * 1024 * 1024);      // 2 MB
    unsigned short* vstack = (unsigned short*)(ws + (size_t)4 * 1024 * 1024);   // 32 MB
    float* pq = (float*)(ws + (size_t)36 * 1024 * 1024);                        // 8 MB
    float* pk = (float*)(ws + (size_t)44 * 1024 * 1024);                        // 8 MB

    qk_part<<<B_ * 16 * 4, 256, 0, stream>>>(x1, x2, Wq, Wk, pq, pk);
    qk_reduce<<<(B_ * N_ * 4) / 256, 256, 0, stream>>>(pq, pk, bq, bk, qbf, kbf);
    v_kernel<<<B_ * 16 * 16 * 2, 256, 0, stream>>>(x1, x2, Wv1, bv1, Wv2, bv2, vstack);
    fused_pv<<<256, 512, 0, stream>>>(qbf, kbf, vstack, x1, x2, out1, out2, att);
}

// Round 6
// 445.798 us; speedup vs baseline: 1.6440x; 1.2770x over previous
//
#include <hip/hip_runtime.h>
#include <hip/hip_bf16.h>

#define B_ 8
#define C_ 256
#define N_ 4096
#define D_ 16
#define TWO_C 512

typedef __bf16 bf16x8 __attribute__((ext_vector_type(8)));
typedef __bf16 bf16x4 __attribute__((ext_vector_type(4)));
typedef float f32x4 __attribute__((ext_vector_type(4)));
typedef unsigned short u16x4 __attribute__((ext_vector_type(4)));

static __device__ __forceinline__ unsigned short f2bf_rtn(float f) {
    unsigned int u = __builtin_bit_cast(unsigned int, f);
    u += 0x7fffu + ((u >> 16) & 1u);
    return (unsigned short)(u >> 16);
}

__device__ __forceinline__ void gld16(const void* g, void* l) {
    __builtin_amdgcn_global_load_lds(
        (const __attribute__((address_space(1))) unsigned int*)g,
        (__attribute__((address_space(3))) unsigned int*)l, 16, 0, 0);
}

#define MF(K, Q) __builtin_amdgcn_mfma_f32_16x16x32_bf16((K), (Q), zerov, 0, 0, 0)

// ---------------------------------------------------------------------------
// Kernel 0: Wv1/Wv2 -> bf16 stacked [512][256]. grid = 64 blocks of 256.
// ---------------------------------------------------------------------------
__global__ __launch_bounds__(256) void wconv(
    const float* __restrict__ Wv1, const float* __restrict__ Wv2,
    unsigned short* __restrict__ Wbf)
{
    const int i = blockIdx.x * 256 + threadIdx.x;   // f32x4 group, 16384 total
    f32x4 a = ((const f32x4*)Wv1)[i];
    f32x4 b = ((const f32x4*)Wv2)[i];
    u16x4 ua = { f2bf_rtn(a[0]), f2bf_rtn(a[1]), f2bf_rtn(a[2]), f2bf_rtn(a[3]) };
    u16x4 ub = { f2bf_rtn(b[0]), f2bf_rtn(b[1]), f2bf_rtn(b[2]), f2bf_rtn(b[3]) };
    ((u16x4*)Wbf)[i] = ua;
    ((u16x4*)Wbf)[16384 + i] = ub;
}

// ---------------------------------------------------------------------------
// Kernel 1a: partial q/k over a 128-wide c-chunk + side-write x as bf16
// TRANSPOSED xbfT[b][n][512] (c-contiguous; x1 cols 0-255, x2 cols 256-511).
// xbfT lives in the att region of d_out (overwritten later by phase 2).
// grid = B*16*4 = 512 blocks.
// ---------------------------------------------------------------------------
__global__ __launch_bounds__(256) void qk_part(
    const float* __restrict__ x1, const float* __restrict__ x2,
    const float* __restrict__ Wq, const float* __restrict__ Wk,
    float* __restrict__ pq, float* __restrict__ pk,
    unsigned short* __restrict__ xbfT)
{
    const int tid = threadIdx.x;
    const int bid = blockIdx.x;
    const int ch = bid & 3;
    const int nt = (bid >> 2) & 15;
    const int b  = bid >> 6;
    const int n  = nt * 256 + tid;

    const float* xs  = (ch < 2) ? x1 : x2;
    const int xoff = (ch & 1) * 128;
    const int wcol = ch * 128;          // stacked column base (== (ch>>1)*256 + xoff)

    const float* px = xs + ((size_t)b * C_ + xoff) * N_ + n;
    unsigned short* xT = xbfT + ((size_t)b * N_ + n) * TWO_C + wcol;

    float aq[D_], ak[D_];
#pragma unroll
    for (int d = 0; d < D_; ++d) { aq[d] = 0.f; ak[d] = 0.f; }

    for (int c8 = 0; c8 < 16; ++c8) {
        unsigned short xb[8];
#pragma unroll
        for (int j = 0; j < 8; ++j) {
            const int c = c8 * 8 + j;
            float xv = px[(size_t)c * N_];
            xb[j] = f2bf_rtn(xv);
#pragma unroll
            for (int d = 0; d < D_; ++d) {
                aq[d] += Wq[d * TWO_C + wcol + c] * xv;
                ak[d] += Wk[d * TWO_C + wcol + c] * xv;
            }
        }
        u16x4 lo = { xb[0], xb[1], xb[2], xb[3] };
        u16x4 hi = { xb[4], xb[5], xb[6], xb[7] };
        *(u16x4*)(xT + c8 * 8)     = lo;
        *(u16x4*)(xT + c8 * 8 + 4) = hi;
    }

    f32x4* q4 = (f32x4*)pq + (size_t)ch * B_ * N_ * 4 + ((size_t)b * N_ + n) * 4;
    f32x4* k4 = (f32x4*)pk + (size_t)ch * B_ * N_ * 4 + ((size_t)b * N_ + n) * 4;
#pragma unroll
    for (int j = 0; j < 4; ++j) {
        f32x4 tq = { aq[4*j], aq[4*j+1], aq[4*j+2], aq[4*j+3] };
        f32x4 tk = { ak[4*j], ak[4*j+1], ak[4*j+2], ak[4*j+3] };
        q4[j] = tq;
        k4[j] = tk;
    }
}

// ---------------------------------------------------------------------------
// Kernel 1b: reduce 4 partials + bias, emit bf16 q/k in [B][N][32] layout
// (d = 16..31 zero-padded for the K=32 MFMA). grid = 512 blocks of 256.
// ---------------------------------------------------------------------------
__global__ __launch_bounds__(256) void qk_reduce(
    const float* __restrict__ pq, const float* __restrict__ pk,
    const float* __restrict__ bq, const float* __restrict__ bk,
    unsigned short* __restrict__ qbf, unsigned short* __restrict__ kbf)
{
    const int tg = blockIdx.x * 256 + threadIdx.x;  // f32x4 group index
    const int row = tg >> 2;                        // b*N + n
    const int d4  = tg & 3;
    const f32x4* pq4 = (const f32x4*)pq;
    const f32x4* pk4 = (const f32x4*)pk;
    f32x4 q = ((const f32x4*)bq)[d4];
    f32x4 k = ((const f32x4*)bk)[d4];
    const size_t stride = (size_t)B_ * N_ * 4;
#pragma unroll
    for (int ch = 0; ch < 4; ++ch) {
        q += pq4[ch * stride + tg];
        k += pk4[ch * stride + tg];
    }
    u16x4 qo = { f2bf_rtn(q[0]), f2bf_rtn(q[1]), f2bf_rtn(q[2]), f2bf_rtn(q[3]) };
    u16x4 ko = { f2bf_rtn(k[0]), f2bf_rtn(k[1]), f2bf_rtn(k[2]), f2bf_rtn(k[3]) };
    u16x4 z  = { 0, 0, 0, 0 };
    *(u16x4*)(qbf + (size_t)row * 32 + d4 * 4)      = qo;
    *(u16x4*)(qbf + (size_t)row * 32 + 16 + d4 * 4) = z;
    *(u16x4*)(kbf + (size_t)row * 32 + d4 * 4)      = ko;
    *(u16x4*)(kbf + (size_t)row * 32 + 16 + d4 * 4) = z;
}

// ---------------------------------------------------------------------------
// Kernel 2: v = Wv @ x + bv via MFMA, LDS-free.
// A-frag = Wbf rows (c-contiguous), B-frag = xbfT rows (c-contiguous),
// both direct 16B loads. D: col = n, row = cout. grid = 1024 blocks
// (b x half x 64 ntiles) of 256 (4 waves, each 64 couts x 64 n).
// ---------------------------------------------------------------------------
__global__ __launch_bounds__(256) void v_mfma(
    const unsigned short* __restrict__ Wbf,
    const unsigned short* __restrict__ xbfT,
    const float* __restrict__ bv1, const float* __restrict__ bv2,
    unsigned short* __restrict__ vstack)
{
    const int tid  = threadIdx.x;
    const int lane = tid & 63;
    const int wid  = tid >> 6;
    const int bid  = blockIdx.x;
    const int b    = bid >> 7;
    const int half = (bid >> 6) & 1;
    const int n0   = (bid & 63) * 64;
    const int col  = lane & 15;
    const int grp  = lane >> 4;
    const int koff = grp * 8;

    const unsigned short* pa[4];
    const unsigned short* pb[4];
#pragma unroll
    for (int ai = 0; ai < 4; ++ai)
        pa[ai] = Wbf + (size_t)(half * 256 + wid * 64 + ai * 16 + col) * 256 + koff;
#pragma unroll
    for (int bj = 0; bj < 4; ++bj)
        pb[bj] = xbfT + ((size_t)b * N_ + n0 + bj * 16 + col) * TWO_C + half * 256 + koff;

    f32x4 acc[4][4];
#pragma unroll
    for (int ai = 0; ai < 4; ++ai)
#pragma unroll
        for (int bj = 0; bj < 4; ++bj)
            acc[ai][bj] = (f32x4){0.f, 0.f, 0.f, 0.f};

#pragma unroll
    for (int s = 0; s < 8; ++s) {
        bf16x8 af[4], bfr[4];
#pragma unroll
        for (int ai = 0; ai < 4; ++ai) af[ai] = *(const bf16x8*)(pa[ai] + s * 32);
#pragma unroll
        for (int bj = 0; bj < 4; ++bj) bfr[bj] = *(const bf16x8*)(pb[bj] + s * 32);
#pragma unroll
        for (int ai = 0; ai < 4; ++ai)
#pragma unroll
            for (int bj = 0; bj < 4; ++bj)
                acc[ai][bj] = __builtin_amdgcn_mfma_f32_16x16x32_bf16(
                    af[ai], bfr[bj], acc[ai][bj], 0, 0, 0);
    }

    const float* bias = half ? bv2 : bv1;
#pragma unroll
    for (int ai = 0; ai < 4; ++ai) {
        const int cb = wid * 64 + ai * 16 + grp * 4;   // within-half cout
#pragma unroll
        for (int r = 0; r < 4; ++r) {
            const float bv = bias[cb + r];
            unsigned short* vr = vstack + ((size_t)b * 512 + half * 256 + cb + r) * N_;
#pragma unroll
            for (int bj = 0; bj < 4; ++bj)
                vr[n0 + bj * 16 + col] = f2bf_rtn(acc[ai][bj][r] + bv);
        }
    }
}

// ---------------------------------------------------------------------------
// Kernel 3: FUSED attention + PV, single barrier per K-step.
// Step t: {ds_read A(t),P(t) frags} || {gld16 A(t+1)} || {E(t+1) MFMA + exp +
// ds_write P(t+1) -> Bsm[nxt]} || {32 PV MFMA} -> one vmcnt0/lgkm0 + barrier.
// The E/exp chain is off the critical path (pipelined one step ahead).
// Epilogue: out = acc*inv + x. Phase 2: recompute e, stream normalized att.
// grid = 256 blocks (8b x 2ct x 16nt), 512 threads.
// ---------------------------------------------------------------------------
__global__ __launch_bounds__(512) void fused_pv(
    const unsigned short* __restrict__ qbf,
    const unsigned short* __restrict__ kbf,
    const unsigned short* __restrict__ vstack,
    const float* __restrict__ x1, const float* __restrict__ x2,
    float* __restrict__ out1, float* __restrict__ out2,
    float* __restrict__ att)
{
    __shared__ unsigned short Asm[2][256 * 32];  // 2 x 16 KB, V tile
    __shared__ unsigned short Bsm[2][256 * 32];  // 2 x 16 KB, P tile
    __shared__ float sinv[256];

    const int tid  = threadIdx.x;
    const int lane = tid & 63;
    const int wid  = tid >> 6;
    const int wr   = wid >> 2;      // 0..1 : c-offset *128
    const int wc   = wid & 3;       // 0..3 : n-offset *64
    const int col  = lane & 15;
    const int grp  = lane >> 4;

    // bijective XCD swizzle: nwg=256, 32/XCD -> one batch per XCD
    const int bid  = blockIdx.x;
    const int orig = (bid & 7) * 32 + (bid >> 3);
    const int nt = orig & 15;
    const int ct = (orig >> 4) & 1;
    const int b  = orig >> 5;
    const int n0 = nt * 256;

    const f32x4 zerov = {0.f, 0.f, 0.f, 0.f};

    // q fragments (B-operand of energy MFMA), one per 16-n subtile
    const bf16x8 qf0 = *(const bf16x8*)(qbf + ((size_t)b * N_ + n0 + wid * 32 + col) * 32 + grp * 8);
    const bf16x8 qf1 = *(const bf16x8*)(qbf + ((size_t)b * N_ + n0 + wid * 32 + 16 + col) * 32 + grp * 8);

    const unsigned short* kbase = kbf + ((size_t)b * N_ + col) * 32 + grp * 8;

    // A (V) staging: pre-swizzled global source, linear LDS dest
    const unsigned short* Vb = vstack + ((size_t)b * 512 + ct * 256) * N_;
    const int q1 = tid + 512;
    const unsigned short* pa0 = Vb + (size_t)(tid >> 2) * N_ + (((tid & 3) ^ ((tid >> 2) & 3)) * 8);
    const unsigned short* pa1 = Vb + (size_t)(q1 >> 2) * N_ + (((q1 & 3) ^ ((q1 >> 2) & 3)) * 8);

    // Bsm write byte-offsets (relative to buffer base); rows nl0 / nl0+16.
    // (nl&3) == (col&3) since nl = wid*32 (+16) + col.
    const int nl0 = wid * 32 + col;
    const int bwA = nl0 * 64 + ((((grp >> 1)) ^ (col & 3)) << 4) + (grp & 1) * 8;
    const int bwB = bwA ^ 32;    // m +16 half: 16B-unit index XOR 2

    // fragment read byte-offsets (relative): base + ai*1024 / bj*1024
    const int raBase = (wr * 128 + col) * 64 + ((grp ^ (col & 3)) << 4);
    const int rbBase = (wc * 64  + col) * 64 + ((grp ^ (col & 3)) << 4);

    f32x4 acc[8][4];
#pragma unroll
    for (int ai = 0; ai < 8; ++ai)
#pragma unroll
        for (int bj = 0; bj < 4; ++bj)
            acc[ai][bj] = zerov;

    float rsum0 = 0.f, rsum1 = 0.f;

#define EMITB(E, RS, BASE, OFF) do {                                          \
    float p0 = __expf((E)[0]), p1 = __expf((E)[1]);                           \
    float p2 = __expf((E)[2]), p3 = __expf((E)[3]);                           \
    RS += (p0 + p1) + (p2 + p3);                                              \
    bf16x4 pkv = { (__bf16)p0, (__bf16)p1, (__bf16)p2, (__bf16)p3 };          \
    *(bf16x4*)((char*)(BASE) + (OFF)) = pkv;                                  \
} while (0)

    // ---- prologue: stage A(0), E(0) -> Bsm[0], prefetch k(1) ----
    gld16(pa0, &Asm[0][tid * 8]);
    gld16(pa1, &Asm[0][tid * 8 + 4096]);
    pa0 += 32; pa1 += 32;
    bf16x8 kA0 = *(const bf16x8*)kbase;
    bf16x8 kA1 = *(const bf16x8*)(kbase + 512);
    const unsigned short* kp = kbase + 1024;
    bf16x8 kB0, kB1;
    {
        f32x4 e00 = MF(kA0, qf0);
        f32x4 e01 = MF(kA1, qf0);
        f32x4 e10 = MF(kA0, qf1);
        f32x4 e11 = MF(kA1, qf1);
        kB0 = *(const bf16x8*)kp;
        kB1 = *(const bf16x8*)(kp + 512);
        kp += 1024;
        EMITB(e00, rsum0, &Bsm[0][0], bwA);
        EMITB(e01, rsum0, &Bsm[0][0], bwB);
        EMITB(e10, rsum1, &Bsm[0][0], bwA + 1024);
        EMITB(e11, rsum1, &Bsm[0][0], bwB + 1024);
    }
    __syncthreads();

    auto step = [&](const unsigned short* AsCur, unsigned short* AsNxt,
                    const unsigned short* BsCur, unsigned short* BsNxt,
                    const bf16x8& kc0, const bf16x8& kc1,
                    bf16x8& kn0, bf16x8& kn1, bool doNext) {
        // (1) PV fragment reads for this step
        bf16x8 bfr[4], af0[4], af1[4];
#pragma unroll
        for (int bj = 0; bj < 4; ++bj)
            bfr[bj] = *(const bf16x8*)((const char*)BsCur + rbBase + bj * 1024);
#pragma unroll
        for (int ai = 0; ai < 4; ++ai)
            af0[ai] = *(const bf16x8*)((const char*)AsCur + raBase + ai * 1024);
        // (2) stage A(t+1)
        if (doNext) {
            gld16(pa0, AsNxt + tid * 8);
            gld16(pa1, AsNxt + tid * 8 + 4096);
            pa0 += 32; pa1 += 32;
        }
        // (3) E(t+1) + exp + pack -> Bsm[nxt]; prefetch k(t+2)
        if (doNext) {
            f32x4 e00 = MF(kc0, qf0);
            f32x4 e01 = MF(kc1, qf0);
            f32x4 e10 = MF(kc0, qf1);
            f32x4 e11 = MF(kc1, qf1);
            kn0 = *(const bf16x8*)kp;
            kn1 = *(const bf16x8*)(kp + 512);
            kp += 1024;
            EMITB(e00, rsum0, BsNxt, bwA);
            EMITB(e01, rsum0, BsNxt, bwB);
            EMITB(e10, rsum1, BsNxt, bwA + 1024);
            EMITB(e11, rsum1, BsNxt, bwB + 1024);
        }
        // (4) PV MFMAs
#pragma unroll
        for (int ai = 0; ai < 4; ++ai)
#pragma unroll
            for (int bj = 0; bj < 4; ++bj)
                acc[ai][bj] = __builtin_amdgcn_mfma_f32_16x16x32_bf16(
                    af0[ai], bfr[bj], acc[ai][bj], 0, 0, 0);
#pragma unroll
        for (int ai = 0; ai < 4; ++ai)
            af1[ai] = *(const bf16x8*)((const char*)AsCur + raBase + (4 + ai) * 1024);
#pragma unroll
        for (int ai = 0; ai < 4; ++ai)
#pragma unroll
            for (int bj = 0; bj < 4; ++bj)
                acc[4 + ai][bj] = __builtin_amdgcn_mfma_f32_16x16x32_bf16(
                    af1[ai], bfr[bj], acc[4 + ai][bj], 0, 0, 0);
        // (5) single fence per step
        if (doNext) {
            asm volatile("s_waitcnt vmcnt(0) lgkmcnt(0)" ::: "memory");
            __builtin_amdgcn_s_barrier();
            __builtin_amdgcn_sched_barrier(0);
        }
    };

    for (int tt = 0; tt < 64; ++tt) {
        step(&Asm[0][0], &Asm[1][0], &Bsm[0][0], &Bsm[1][0], kB0, kB1, kA0, kA1, true);
        step(&Asm[1][0], &Asm[0][0], &Bsm[1][0], &Bsm[0][0], kA0, kA1, kB0, kB1, tt < 63);
    }

    // ---- rowsums -> inv ----
    rsum0 += __shfl_xor(rsum0, 16); rsum0 += __shfl_xor(rsum0, 32);
    rsum1 += __shfl_xor(rsum1, 16); rsum1 += __shfl_xor(rsum1, 32);
    const float inv0 = 1.f / rsum0;
    const float inv1 = 1.f / rsum1;
    if (lane < 16) {
        sinv[wid * 32 + lane]      = inv0;
        sinv[wid * 32 + 16 + lane] = inv1;
    }
    __syncthreads();

    // ---- epilogue: out = acc * inv + x ----
    float* outp     = ct ? out2 : out1;
    const float* xp = ct ? x2 : x1;
    float sc[4];
#pragma unroll
    for (int bj = 0; bj < 4; ++bj) sc[bj] = sinv[wc * 64 + bj * 16 + col];
#pragma unroll
    for (int ai = 0; ai < 8; ++ai) {
        const int c_l = wr * 128 + ai * 16 + grp * 4;
#pragma unroll
        for (int bj = 0; bj < 4; ++bj) {
            const int n = n0 + wc * 64 + bj * 16 + col;
#pragma unroll
            for (int r = 0; r < 4; ++r) {
                const size_t idx = ((size_t)b * C_ + c_l + r) * N_ + n;
                outp[idx] = acc[ai][bj][r] * sc[bj] + xp[idx];
            }
        }
    }

    // ---- phase 2: recompute e, write normalized att for this ct's m-half ----
    const unsigned short* kp2 = kbase + (size_t)(ct * 2048) * 32;
    float* ar0 = att + (size_t)b * N_ * N_ + (size_t)(n0 + wid * 32 + col) * N_;
    float* ar1 = ar0 + (size_t)16 * N_;

#define WRA(E, ROW, MOFF, INV) do {                                           \
    f32x4 pv = { __expf((E)[0]) * (INV), __expf((E)[1]) * (INV),              \
                 __expf((E)[2]) * (INV), __expf((E)[3]) * (INV) };            \
    *(f32x4*)((ROW) + (MOFF)) = pv;                                           \
} while (0)

    for (int s = 0; s < 64; ++s) {
        const int m0 = ct * 2048 + s * 32;
        bf16x8 k0 = *(const bf16x8*)kp2;
        bf16x8 k1 = *(const bf16x8*)(kp2 + 512);
        kp2 += 1024;
        f32x4 e00 = MF(k0, qf0);
        f32x4 e01 = MF(k1, qf0);
        f32x4 e10 = MF(k0, qf1);
        f32x4 e11 = MF(k1, qf1);
        WRA(e00, ar0, m0 + grp * 4,      inv0);
        WRA(e01, ar0, m0 + 16 + grp * 4, inv0);
        WRA(e10, ar1, m0 + grp * 4,      inv1);
        WRA(e11, ar1, m0 + 16 + grp * 4, inv1);
    }
#undef EMITB
#undef WRA
}

// ---------------------------------------------------------------------------
extern "C" void kernel_launch(void* const* d_in, const int* in_sizes, int n_in,
                              void* d_out, int out_size, void* d_ws, size_t ws_size,
                              hipStream_t stream)
{
    const float* x1  = (const float*)d_in[0];
    const float* x2  = (const float*)d_in[1];
    const float* Wq  = (const float*)d_in[2];
    const float* bq  = (const float*)d_in[3];
    const float* Wk  = (const float*)d_in[4];
    const float* bk  = (const float*)d_in[5];
    const float* Wv1 = (const float*)d_in[6];
    const float* bv1 = (const float*)d_in[7];
    const float* Wv2 = (const float*)d_in[8];
    const float* bv2 = (const float*)d_in[9];

    float* out  = (float*)d_out;
    float* out1 = out;
    float* out2 = out + (size_t)B_ * C_ * N_;
    float* att  = out + 2 * (size_t)B_ * C_ * N_;

    // xbfT (32 MB) scribbles the front of the att region; fused_pv phase 2
    // fully overwrites all of att afterwards.
    unsigned short* xbfT = (unsigned short*)att;

    char* ws = (char*)d_ws;
    unsigned short* qbf = (unsigned short*)ws;                                  // 2 MB [B][N][32]
    unsigned short* kbf = (unsigned short*)(ws + (size_t)2 * 1024 * 1024);      // 2 MB
    unsigned short* vstack = (unsigned short*)(ws + (size_t)4 * 1024 * 1024);   // 32 MB
    float* pq = (float*)(ws + (size_t)36 * 1024 * 1024);                        // 8 MB
    float* pk = (float*)(ws + (size_t)44 * 1024 * 1024);                        // 8 MB
    unsigned short* Wbf = (unsigned short*)(ws + (size_t)52 * 1024 * 1024);     // 256 KB

    wconv<<<64, 256, 0, stream>>>(Wv1, Wv2, Wbf);
    qk_part<<<B_ * 16 * 4, 256, 0, stream>>>(x1, x2, Wq, Wk, pq, pk, xbfT);
    qk_reduce<<<(B_ * N_ * 4) / 256, 256, 0, stream>>>(pq, pk, bq, bk, qbf, kbf);
    v_mfma<<<B_ * 2 * 64, 256, 0, stream>>>(Wbf, xbfT, bv1, bv2, vstack);
    fused_pv<<<256, 512, 0, stream>>>(qbf, kbf, vstack, x1, x2, out1, out2, att);
}